// Round 17
// baseline (454.264 us; speedup 1.0000x reference)
//
#include <hip/hip_runtime.h>
#include <stdint.h>

// B=2 S=2048 E=1024 H=16 DH=64.  M = B*S = 4096.
// ws layout (ushort elems): values 4M | qkin 4M | wqkv 3M | wout 1M | q 4M | k 4M | vt 4M | attn 4M
//   | (optional, if ws allows) po2 4M | po3 4M
// vt layout: [bh][d=64][s=2048]  (V transposed, written coalesced via LDS in gemm_qkv epilogue)
// After gemm_qkv, values/qkin/wqkv are dead -> reused as attn partials: po0=values, po1=qkin, stats=wqkv.

typedef __attribute__((ext_vector_type(8))) short bf16x8;
typedef __attribute__((ext_vector_type(4))) short bf16x4;
typedef __attribute__((ext_vector_type(4))) float f32x4;
typedef __attribute__((ext_vector_type(4))) unsigned short u16x4;

#define DEV __device__ __forceinline__

DEV unsigned short f2bf(float f) {
  uint32_t u = __float_as_uint(f);
  u += 0x7fff + ((u >> 16) & 1);
  return (unsigned short)(u >> 16);
}

DEV float bf2f(unsigned short u) { return __uint_as_float((uint32_t)u << 16); }

DEV float fast_exp2(float x) {
#if __has_builtin(__builtin_amdgcn_exp2f)
  return __builtin_amdgcn_exp2f(x);
#else
  return exp2f(x);
#endif
}

DEV f32x4 mfma16x16x16_bf16(bf16x4 a, bf16x4 b, f32x4 c) {
#if __has_builtin(__builtin_amdgcn_mfma_f32_16x16x16bf16_1k)
  return __builtin_amdgcn_mfma_f32_16x16x16bf16_1k(a, b, c, 0, 0, 0);
#else
  asm("v_mfma_f32_16x16x16_bf16 %0, %1, %2, %0" : "+v"(c) : "v"(a), "v"(b));
  return c;
#endif
}

DEV void gload_lds16(const void* g, void* l) {
  __builtin_amdgcn_global_load_lds(
      (const __attribute__((address_space(1))) uint32_t*)g,
      (__attribute__((address_space(3))) uint32_t*)l, 16, 0, 0);
}

// ---------------- fused: LN+GELU+encodings (blocks 0..4095) | weight f32->bf16 (blocks 4096..8191) ----------------
__global__ __launch_bounds__(256) void preproc_wconv(const float* x, const float* mul, const float* add,
                                                     const float* lw, const float* lb,
                                                     unsigned short* values, unsigned short* qkin,
                                                     const float* w1, const float* w2,
                                                     unsigned short* o1, unsigned short* o2) {
  int t = threadIdx.x;
  if (blockIdx.x >= 4096) {
    int i = (blockIdx.x - 4096) * 256 + t;   // over f32x4 chunks
    const int n1 = 3145728 / 4;              // in_proj_w chunks
    f32x4 v;
    if (i < n1) v = ((const f32x4*)w1)[i];
    else        v = ((const f32x4*)w2)[i - n1];
    u16x4 r;
#pragma unroll
    for (int j = 0; j < 4; ++j) r[j] = f2bf(v[j]);
    if (i < n1) ((u16x4*)o1)[i] = r;
    else        ((u16x4*)o2)[i - n1] = r;
    return;
  }
  int row = blockIdx.x;                 // 4096 rows
  size_t base = (size_t)row * 1024;
  f32x4 v = ((const f32x4*)(x + base))[t];
  float s  = v[0] + v[1] + v[2] + v[3];
  float s2 = v[0]*v[0] + v[1]*v[1] + v[2]*v[2] + v[3]*v[3];
#pragma unroll
  for (int off = 1; off < 64; off <<= 1) {
    s  += __shfl_xor(s, off);
    s2 += __shfl_xor(s2, off);
  }
  __shared__ float rs[4], rs2[4];
  if ((t & 63) == 0) { rs[t >> 6] = s; rs2[t >> 6] = s2; }
  __syncthreads();
  s  = rs[0] + rs[1] + rs[2] + rs[3];
  s2 = rs2[0] + rs2[1] + rs2[2] + rs2[3];
  float mean = s * 0.0009765625f;
  float var  = s2 * 0.0009765625f - mean * mean;
  float rstd = rsqrtf(var + 1e-5f);
  f32x4 mu = ((const f32x4*)(mul + base))[t];
  f32x4 ad = ((const f32x4*)(add + base))[t];
  f32x4 w4 = ((const f32x4*)lw)[t];
  f32x4 b4 = ((const f32x4*)lb)[t];
  u16x4 vo, qo;
#pragma unroll
  for (int i = 0; i < 4; ++i) {
    float d = (v[i] - mean) * rstd * w4[i] + b4[i];
    float g = 0.5f * d * (1.0f + erff(d * 0.70710678118f));  // exact gelu
    vo[i] = f2bf(g);
    qo[i] = f2bf(g * mu[i] + ad[i]);
  }
  ((u16x4*)(values + base))[t] = vo;
  ((u16x4*)(qkin   + base))[t] = qo;
}

// ---------------- QKV projection GEMM: 64x128 tile, 8 waves, double-buffered, XCD-chunked ----------------
// Q is pre-scaled by 1/sqrt(DH) * log2(e) so attention works in exp2 domain.
#define QSCALE 0.18033688011112042f

DEV void qkv_stage(const unsigned short* A, const unsigned short* W,
                   int m0, int n0, int k0, unsigned short* buf, int t) {
  int w = t >> 6;                        // wave 0..7
  unsigned short* ldsA = buf;
  unsigned short* ldsB = buf + 64 * 64;
  {
    int idx = t;                         // 0..511 chunks of A (64x64)
    int r = idx >> 3;                    // 0..63
    int slot = (idx & 7) ^ (r & 7);
    gload_lds16(A + (size_t)(m0 + r) * 1024 + k0 + slot * 8,
                (char*)ldsA + w * 1024);
  }
#pragma unroll
  for (int i = 0; i < 2; ++i) {
    int idx = i * 512 + t;               // 0..1023 chunks of W (128x64)
    int r = idx >> 3;                    // 0..127
    int slot = (idx & 7) ^ (r & 7);
    gload_lds16(W + (size_t)(n0 + r) * 1024 + k0 + slot * 8,
                (char*)ldsB + i * 8192 + w * 1024);
  }
}

__global__ __launch_bounds__(512) void gemm_qkv(const unsigned short* Aqk, const unsigned short* Av,
                                                const unsigned short* W, const float* bias,
                                                unsigned short* qws, unsigned short* kws,
                                                unsigned short* vtws) {
  __shared__ unsigned short lds[2][(64 + 128) * 64];   // 48 KB double-buffered
  // XCD swizzle: each XCD owns 3 n-tiles (W panels L2-resident) x all 64 m-tiles.
  int id = blockIdx.x;                 // 0..1535
  int xcd = id & 7, rr = id >> 3;      // rr 0..191
  int bx = xcd * 3 + (rr % 3);         // n-tile 0..23
  int by = rr / 3;                     // m-tile 0..63
  int n0 = bx * 128;
  int m0 = by * 64;
  const unsigned short* A = (n0 < 2048) ? Aqk : Av;
  int t = threadIdx.x, lane = t & 63, w = t >> 6;   // w 0..7
  int wr = w & 3, wc = w >> 2;         // wave owns rows wr*16..+15, cols wc*64..+63
  int l15 = lane & 15, l4 = lane >> 4;
  f32x4 z = {0.f, 0.f, 0.f, 0.f};
  f32x4 acc[4];
#pragma unroll
  for (int nn = 0; nn < 4; ++nn) acc[nn] = z;

  qkv_stage(A, W, m0, n0, 0, &lds[0][0], t);
  __syncthreads();

  for (int it = 0; it < 16; ++it) {
    int cur = it & 1;
    if (it < 15) qkv_stage(A, W, m0, n0, (it + 1) * 64, &lds[cur ^ 1][0], t);
    const unsigned short* ldsA = &lds[cur][0];
    const unsigned short* ldsB = &lds[cur][64 * 64];
#pragma unroll
    for (int kk = 0; kk < 2; ++kk) {
      bf16x8 af, bfr[4];
      int kb = kk * 64 + l4 * 16;
      {
        int r = wr * 16 + l15;
        af = *(const bf16x8*)((const char*)ldsA + r * 128 + (kb ^ ((r & 7) << 4)));
      }
#pragma unroll
      for (int nn = 0; nn < 4; ++nn) {
        int r = wc * 64 + nn * 16 + l15;
        bfr[nn] = *(const bf16x8*)((const char*)ldsB + r * 128 + (kb ^ ((r & 7) << 4)));
      }
#pragma unroll
      for (int nn = 0; nn < 4; ++nn)
        acc[nn] = __builtin_amdgcn_mfma_f32_16x16x32_bf16(af, bfr[nn], acc[nn], 0, 0, 0);
    }
    __syncthreads();
  }

  int region = n0 >> 10;                       // block-uniform
  int bb = m0 >> 11, s0 = m0 & 2047;

  if (region == 2) {
    // ---- V: transpose through LDS (64 s x 128 c), then coalesced VT stores ----
    unsigned short* sc = &lds[0][0];
#pragma unroll
    for (int nn = 0; nn < 4; ++nn) {
      int col = wc * 64 + nn * 16 + l15;
      float bs = bias[n0 + col];
#pragma unroll
      for (int reg = 0; reg < 4; ++reg) {
        int row = wr * 16 + l4 * 4 + reg;
        *(unsigned short*)((char*)sc + row * 256 + ((col * 2) ^ ((row & 7) << 4))) =
            f2bf(acc[nn][reg] + bs);
      }
    }
    __syncthreads();
    // thread t: column c = t>>2 (local d), quarter ql = t&3 (16 s each)
    int c = t >> 2, ql = t & 3;
    int e0 = n0 - 2048;
    int h = (e0 + c) >> 6, d = (e0 + c) & 63;
    unsigned short* dst = vtws + ((size_t)(bb * 16 + h) * 64 + d) * 2048 + s0 + ql * 16;
#pragma unroll
    for (int j0 = 0; j0 < 16; j0 += 8) {
      bf16x8 pk;
#pragma unroll
      for (int j = 0; j < 8; ++j) {
        int s = ql * 16 + j0 + j;
        pk[j] = *(const short*)((const char*)sc + s * 256 + ((c * 2) ^ ((s & 7) << 4)));
      }
      *(bf16x8*)(dst + j0) = pk;
    }
  } else {
    // ---- Q/K: direct stores (lane-consecutive d -> coalesced 32B runs) ----
    unsigned short* dst0 = region == 0 ? qws : kws;
    float scl = region == 0 ? QSCALE : 1.0f;
    int row0 = m0 + wr * 16 + l4 * 4;
    int sr = row0 & 2047;
#pragma unroll
    for (int nn = 0; nn < 4; ++nn) {
      int col = n0 + wc * 64 + nn * 16 + l15;
      float bs = bias[col];
      int e = col & 1023;
      int h = e >> 6, d = e & 63;
#pragma unroll
      for (int reg = 0; reg < 4; ++reg)
        dst0[(((size_t)(bb * 16 + h)) * 2048 + sr + reg) * 64 + d] = f2bf((acc[nn][reg] + bs) * scl);
    }
  }
}

// ---------------- flash attention: templated KV block (64 or 32), split-KV across blocks ----------------
template<int KVB>
DEV void stage_kT(const unsigned short* Kp, int kv0, unsigned short* buf, int t) {
  int w = t >> 6;
#pragma unroll
  for (int i = 0; i < KVB / 32; ++i) {
    int idx = i * 256 + t;
    int r = idx >> 3;                    // kv row
    int slot = (idx & 7) ^ (r & 7);
    gload_lds16(Kp + (size_t)(kv0 + r) * 64 + slot * 8,
                (char*)buf + i * 4096 + w * 1024);
  }
}

template<int KVB>
DEV void stage_vtT(const unsigned short* Vt, int kv0, unsigned short* buf, int t) {
  int w = t >> 6;
  constexpr int CPR = KVB / 8;           // 16B chunks per VT row
#pragma unroll
  for (int i = 0; i < KVB / 32; ++i) {
    int idx = i * 256 + t;
    int r = idx / CPR;                   // d row 0..63
    int g = idx % CPR;
    int slot = g ^ (r & (CPR - 1));
    gload_lds16(Vt + (size_t)r * 2048 + kv0 + slot * 8,
                (char*)buf + i * 4096 + w * 1024);
  }
}

template<int KVB>
DEV void attn_computeT(const unsigned short* kbuf, const unsigned short* vtbuf,
                       const bf16x8 (&aq)[2][2], f32x4 (&o)[2][4],
                       float (&m_run)[2], f32x4 (&l_run4)[2], const int (&osrc)[4],
                       int l15, int l4) {
  constexpr int NN = KVB / 16;
  constexpr int RS = KVB * 2;            // VT row stride bytes
  constexpr int VM = (RS >> 4) - 1;      // VT swizzle row mask
  const bf16x4 ones4 = {(short)0x3F80, (short)0x3F80, (short)0x3F80, (short)0x3F80};
  f32x4 z = {0.f, 0.f, 0.f, 0.f};
  f32x4 sc[2][NN];
#pragma unroll
  for (int qs = 0; qs < 2; ++qs)
#pragma unroll
    for (int nn = 0; nn < NN; ++nn) sc[qs][nn] = z;
  __builtin_amdgcn_s_setprio(1);
#pragma unroll
  for (int kk = 0; kk < 2; ++kk) {
#pragma unroll
    for (int nn = 0; nn < NN; ++nn) {
      int r = nn * 16 + l15;
      bf16x8 bk = *(const bf16x8*)((const char*)kbuf + r * 128 + ((kk * 64 + l4 * 16) ^ ((r & 7) << 4)));
#pragma unroll
      for (int qs = 0; qs < 2; ++qs)
        sc[qs][nn] = __builtin_amdgcn_mfma_f32_16x16x32_bf16(bk, aq[qs][kk], sc[qs][nn], 0, 0, 0);
    }
  }
  __builtin_amdgcn_s_setprio(0);

  bf16x4 pa[2][NN];
  float pmax[2];
#pragma unroll
  for (int qs = 0; qs < 2; ++qs) {
    float pm = -1e30f;
#pragma unroll
    for (int nn = 0; nn < NN; ++nn)
      pm = fmaxf(pm, fmaxf(fmaxf(sc[qs][nn][0], sc[qs][nn][1]), fmaxf(sc[qs][nn][2], sc[qs][nn][3])));
    pm = fmaxf(pm, __shfl_xor(pm, 16));
    pm = fmaxf(pm, __shfl_xor(pm, 32));
    pmax[qs] = pm;
  }

  if (__any(fmaxf(pmax[0] - m_run[0], pmax[1] - m_run[1]) > 8.0f)) {
#pragma unroll
    for (int qs = 0; qs < 2; ++qs) {
      float mnew = fmaxf(m_run[qs], pmax[qs]);
      float fs = fast_exp2(m_run[qs] - mnew);
      m_run[qs] = mnew;
      float fo[4];
#pragma unroll
      for (int reg = 0; reg < 4; ++reg) fo[reg] = __shfl(fs, osrc[reg]);
#pragma unroll
      for (int reg = 0; reg < 4; ++reg) l_run4[qs][reg] *= fo[reg];
#pragma unroll
      for (int dt = 0; dt < 4; ++dt)
#pragma unroll
        for (int reg = 0; reg < 4; ++reg) o[qs][dt][reg] *= fo[reg];
    }
  }

#pragma unroll
  for (int qs = 0; qs < 2; ++qs) {
#pragma unroll
    for (int nn = 0; nn < NN; ++nn) {
      float p0 = fast_exp2(sc[qs][nn][0] - m_run[qs]);
      float p1 = fast_exp2(sc[qs][nn][1] - m_run[qs]);
      float p2 = fast_exp2(sc[qs][nn][2] - m_run[qs]);
      float p3 = fast_exp2(sc[qs][nn][3] - m_run[qs]);
      pa[qs][nn][0] = (short)(__float_as_uint(p0) >> 16);
      pa[qs][nn][1] = (short)(__float_as_uint(p1) >> 16);
      pa[qs][nn][2] = (short)(__float_as_uint(p2) >> 16);
      pa[qs][nn][3] = (short)(__float_as_uint(p3) >> 16);
    }
  }

  __builtin_amdgcn_s_setprio(1);
  // l-sum via ones-MFMA: D[q][*] = sum_kv P[q][kv]
#pragma unroll
  for (int nn = 0; nn < NN; ++nn)
#pragma unroll
    for (int qs = 0; qs < 2; ++qs)
      l_run4[qs] = mfma16x16x16_bf16(pa[qs][nn], ones4, l_run4[qs]);
#pragma unroll
  for (int dt = 0; dt < 4; ++dt) {
    int r = dt * 16 + l15;
#pragma unroll
    for (int nn = 0; nn < NN; ++nn) {
      bf16x4 vb = *(const bf16x4*)((const char*)vtbuf + r * RS + ((nn * 32 + l4 * 8) ^ ((r & VM) << 4)));
#pragma unroll
      for (int qs = 0; qs < 2; ++qs)
        o[qs][dt] = mfma16x16x16_bf16(pa[qs][nn], vb, o[qs][dt]);
    }
  }
  __builtin_amdgcn_s_setprio(0);
}

template<int KVB>
__global__ __launch_bounds__(256, (KVB == 32 ? 8 : 4)) void attn_kernel(
    const unsigned short* qws, const unsigned short* kws, const unsigned short* vtws,
    unsigned short* po0, unsigned short* po1, unsigned short* po2, unsigned short* po3,
    float* stats, int nsplit) {
  __shared__ unsigned short ldsK[2][KVB * 64];
  __shared__ unsigned short ldsVT[2][64 * KVB];
  int kvspan = 2048 / nsplit;
  int cpx = 4 * nsplit;                // (32*nsplit combos)/8 XCDs
  int id = blockIdx.x;
  int xcd = id & 7, rr = id >> 3;
  int c = xcd * cpx + (rr % cpx);      // combo 0..32*nsplit-1
  int qt = rr / cpx;                   // 0..15
  int bh = c & 31;
  int qq = c >> 5;                     // split index
  int q0 = qt * 128;
  int kvbase = qq * kvspan;
  int t = threadIdx.x;
  int lane = t & 63, w = t >> 6;
  int l15 = lane & 15, l4 = lane >> 4;

  const unsigned short* Qp = qws + ((size_t)bh * 2048 + q0 + w * 32) * 64;
  const unsigned short* Kp = kws + ((size_t)bh * 2048 + kvbase) * 64;
  const unsigned short* Vt = vtws + (size_t)bh * 64 * 2048 + kvbase;

  bf16x8 aq[2][2];
#pragma unroll
  for (int qs = 0; qs < 2; ++qs)
#pragma unroll
    for (int kk = 0; kk < 2; ++kk)
      aq[qs][kk] = *(const bf16x8*)(Qp + (qs * 16 + l15) * 64 + kk * 32 + l4 * 8);

  f32x4 z = {0.f, 0.f, 0.f, 0.f};
  f32x4 o[2][4];
#pragma unroll
  for (int qs = 0; qs < 2; ++qs)
#pragma unroll
    for (int i = 0; i < 4; ++i) o[qs][i] = z;
  float m_run[2] = {-1e30f, -1e30f};
  f32x4 l_run4[2] = {z, z};

  int osrc[4];
#pragma unroll
  for (int reg = 0; reg < 4; ++reg)
    osrc[reg] = (lane & 48) | (((lane >> 4) & 3) << 2) | reg;

  stage_kT<KVB>(Kp, 0, &ldsK[0][0], t);
  stage_vtT<KVB>(Vt, 0, &ldsVT[0][0], t);
  __syncthreads();

  int iters = kvspan / KVB;
  for (int it = 0; it < iters; ++it) {
    int cur = it & 1;
    if (it < iters - 1) {
      stage_kT<KVB>(Kp, (it + 1) * KVB, &ldsK[cur ^ 1][0], t);
      stage_vtT<KVB>(Vt, (it + 1) * KVB, &ldsVT[cur ^ 1][0], t);
    }
    attn_computeT<KVB>(&ldsK[cur][0], &ldsVT[cur][0], aq, o, m_run, l_run4, osrc, l15, l4);
    __syncthreads();
  }

  unsigned short* po = qq == 0 ? po0 : (qq == 1 ? po1 : (qq == 2 ? po2 : po3));
#pragma unroll
  for (int qs = 0; qs < 2; ++qs) {
#pragma unroll
    for (int reg = 0; reg < 4; ++reg) {
      int qg = q0 + w * 32 + qs * 16 + l4 * 4 + reg;
#pragma unroll
      for (int dt = 0; dt < 4; ++dt) {
        int d = dt * 16 + l15;
        po[((size_t)bh * 2048 + qg) * 64 + d] = f2bf(o[qs][dt][reg]);
      }
    }
  }
  if (l4 == 0) {
#pragma unroll
    for (int qs = 0; qs < 2; ++qs) {
      int qg = q0 + w * 32 + qs * 16 + l15;
      size_t si = (((size_t)qq * 32 + bh) * 2048 + qg) * 2;
      stats[si] = m_run[qs];
    }
  }
  if (l15 == 0) {
#pragma unroll
    for (int qs = 0; qs < 2; ++qs) {
#pragma unroll
      for (int reg = 0; reg < 4; ++reg) {
        int qg = q0 + w * 32 + qs * 16 + l4 * 4 + reg;
        size_t si = (((size_t)qq * 32 + bh) * 2048 + qg) * 2;
        stats[si + 1] = l_run4[qs][reg];
      }
    }
  }
}

// ---------------- merge the KV-split partials ----------------
template<int NSPLIT>
__global__ __launch_bounds__(256) void attn_merge(const unsigned short* po0, const unsigned short* po1,
                                                  const unsigned short* po2, const unsigned short* po3,
                                                  const float* stats, unsigned short* attnb) {
  int row = blockIdx.x;            // 4096 = b*2048 + q
  int b = row >> 11, q = row & 2047;
  int t = threadIdx.x;
  int c0 = t * 4;
  int h = c0 >> 6, d = c0 & 63;
  int bh = b * 16 + h;
  float ms[NSPLIT], ls[NSPLIT];
  float m = -1e30f;
#pragma unroll
  for (int s = 0; s < NSPLIT; ++s) {
    size_t si = (((size_t)s * 32 + bh) * 2048 + q) * 2;
    ms[s] = stats[si];
    ls[s] = stats[si + 1];
    m = fmaxf(m, ms[s]);
  }
  float a[NSPLIT];
  float denom = 0.f;
#pragma unroll
  for (int s = 0; s < NSPLIT; ++s) {
    a[s] = fast_exp2(ms[s] - m);
    denom += ls[s] * a[s];
  }
  float inv = 1.0f / denom;
#pragma unroll
  for (int s = 0; s < NSPLIT; ++s) a[s] *= inv;
  size_t off = ((size_t)bh * 2048 + q) * 64 + d;
  const unsigned short* pos[4] = {po0, po1, po2, po3};
  float acc[4] = {0.f, 0.f, 0.f, 0.f};
#pragma unroll
  for (int s = 0; s < NSPLIT; ++s) {
    u16x4 x = *(const u16x4*)(pos[s] + off);
#pragma unroll
    for (int j = 0; j < 4; ++j) acc[j] += bf2f((unsigned short)x[j]) * a[s];
  }
  u16x4 r;
#pragma unroll
  for (int j = 0; j < 4; ++j) r[j] = f2bf(acc[j]);
  *(u16x4*)(attnb + (size_t)row * 1024 + c0) = r;
}

// ---------------- out projection + bias + residual (64x64 tile, 4 blocks/CU, XCD-chunked) ----------------
__global__ __launch_bounds__(256) void gemm_out(const unsigned short* A, const unsigned short* W,
                                                const float* bias, const float* resid, float* out) {
  __shared__ unsigned short ldsA[64 * 64];
  __shared__ unsigned short ldsB[64 * 64];
  // XCD swizzle: each XCD owns 2 n-tiles (W panels L2-resident) x all 64 m-tiles.
  int id = blockIdx.x;                 // 0..1023
  int xcd = id & 7, rr = id >> 3;      // rr 0..127
  int bx = xcd * 2 + (rr & 1);         // n-tile 0..15
  int by = rr >> 1;                    // m-tile 0..63
  int n0 = bx * 64;
  int m0 = by * 64;
  int t = threadIdx.x;
  int lane = t & 63;
  int w = t >> 6;              // wave handles rows w*16..+15, all 64 cols
  int l15 = lane & 15, l4 = lane >> 4;
  f32x4 z = {0.f, 0.f, 0.f, 0.f};
  f32x4 acc[4];
#pragma unroll
  for (int nn = 0; nn < 4; ++nn) acc[nn] = z;

  for (int k0 = 0; k0 < 1024; k0 += 64) {
#pragma unroll
    for (int i = 0; i < 2; ++i) {
      int idx = i * 256 + t;
      int r = idx >> 3;
      int slot = (idx & 7) ^ (r & 7);
      gload_lds16(A + (size_t)(m0 + r) * 1024 + k0 + slot * 8,
                  (char*)ldsA + i * 4096 + w * 1024);
    }
#pragma unroll
    for (int i = 0; i < 2; ++i) {
      int idx = i * 256 + t;
      int r = idx >> 3;
      int slot = (idx & 7) ^ (r & 7);
      gload_lds16(W + (size_t)(n0 + r) * 1024 + k0 + slot * 8,
                  (char*)ldsB + i * 4096 + w * 1024);
    }
    __syncthreads();
#pragma unroll
    for (int kk = 0; kk < 2; ++kk) {
      bf16x8 af, bfr[4];
      int kb = kk * 64 + l4 * 16;
      {
        int r = w * 16 + l15;
        af = *(const bf16x8*)((const char*)ldsA + r * 128 + (kb ^ ((r & 7) << 4)));
      }
#pragma unroll
      for (int nn = 0; nn < 4; ++nn) {
        int r = nn * 16 + l15;
        bfr[nn] = *(const bf16x8*)((const char*)ldsB + r * 128 + (kb ^ ((r & 7) << 4)));
      }
#pragma unroll
      for (int nn = 0; nn < 4; ++nn)
        acc[nn] = __builtin_amdgcn_mfma_f32_16x16x32_bf16(af, bfr[nn], acc[nn], 0, 0, 0);
    }
    __syncthreads();
  }

#pragma unroll
  for (int nn = 0; nn < 4; ++nn) {
    int col = n0 + nn * 16 + l15;
    float bs = bias[col];
#pragma unroll
    for (int reg = 0; reg < 4; ++reg) {
      int r = m0 + w * 16 + l4 * 4 + reg;
      size_t off = (size_t)r * 1024 + col;
      out[off] = acc[nn][reg] + bs + resid[off];
    }
  }
}

extern "C" void kernel_launch(void* const* d_in, const int* in_sizes, int n_in,
                              void* d_out, int out_size, void* d_ws, size_t ws_size,
                              hipStream_t stream) {
  const float* in_feats   = (const float*)d_in[0];
  const float* mul_encs   = (const float*)d_in[1];
  const float* add_encs   = (const float*)d_in[2];
  const float* ln_w       = (const float*)d_in[3];
  const float* ln_b       = (const float*)d_in[4];
  const float* in_proj_w  = (const float*)d_in[5];
  const float* in_proj_b  = (const float*)d_in[6];
  const float* out_proj_w = (const float*)d_in[7];
  const float* out_proj_b = (const float*)d_in[8];
  float* out = (float*)d_out;

  unsigned short* ws = (unsigned short*)d_ws;
  unsigned short* values = ws;
  unsigned short* qkin   = values + 4194304;
  unsigned short* wqkv   = qkin + 4194304;
  unsigned short* wout   = wqkv + 3145728;
  unsigned short* qws    = wout + 1048576;
  unsigned short* kws    = qws + 4194304;
  unsigned short* vtws   = kws + 4194304;
  unsigned short* attnb  = vtws + 4194304;   // ends at 29,360,128 ushorts

  // dead-after-gemm_qkv regions reused by attention partials:
  unsigned short* po0   = values;            // 8MB
  unsigned short* po1   = qkin;              // 8MB
  float*          stats = (float*)wqkv;      // up to 2MB (fits in 6MB)

  // 4-way split needs two extra 8MB partial buffers beyond the 56MB base layout.
  bool four = ws_size >= 75497472ull;        // 37,748,736 ushorts * 2B
  unsigned short* po2 = four ? (attnb + 4194304) : po0;   // dummy when unused
  unsigned short* po3 = four ? (attnb + 8388608) : po1;

  preproc_wconv<<<8192, 256, 0, stream>>>(in_feats, mul_encs, add_encs, ln_w, ln_b,
                                          values, qkin, in_proj_w, out_proj_w, wqkv, wout);
  gemm_qkv<<<1536, 512, 0, stream>>>(qkin, values, wqkv, in_proj_b, qws, kws, vtws);
  if (four) {
    attn_kernel<32><<<2048, 256, 0, stream>>>(qws, kws, vtws, po0, po1, po2, po3, stats, 4);
    attn_merge<4><<<4096, 256, 0, stream>>>(po0, po1, po2, po3, stats, attnb);
  } else {
    attn_kernel<64><<<1024, 256, 0, stream>>>(qws, kws, vtws, po0, po1, po2, po3, stats, 2);
    attn_merge<2><<<4096, 256, 0, stream>>>(po0, po1, po2, po3, stats, attnb);
  }
  gemm_out<<<1024, 256, 0, stream>>>(attnb, wout, out_proj_b, in_feats, out);
}

// Round 18
// 141.313 us; speedup vs baseline: 3.2146x; 3.2146x over previous
//
#include <hip/hip_runtime.h>
#include <stdint.h>

// B=2 S=2048 E=1024 H=16 DH=64.  M = B*S = 4096.
// ws layout (ushort elems): values 4M | qkin 4M | wqkv 3M | wout 1M | q 4M | k 4M | vt 4M | attn 4M
//   | (optional, if ws allows) po2 4M | po3 4M
// vt layout: [bh][d=64][s=2048]  (V transposed, written coalesced via LDS in gemm_qkv epilogue)
// After gemm_qkv, values/qkin/wqkv are dead -> reused as attn partials: po0=values, po1=qkin, stats=wqkv.

typedef __attribute__((ext_vector_type(8))) short bf16x8;
typedef __attribute__((ext_vector_type(4))) short bf16x4;
typedef __attribute__((ext_vector_type(4))) float f32x4;
typedef __attribute__((ext_vector_type(4))) unsigned short u16x4;

#define DEV __device__ __forceinline__

DEV unsigned short f2bf(float f) {
  uint32_t u = __float_as_uint(f);
  u += 0x7fff + ((u >> 16) & 1);
  return (unsigned short)(u >> 16);
}

DEV float bf2f(unsigned short u) { return __uint_as_float((uint32_t)u << 16); }

DEV float fast_exp2(float x) {
#if __has_builtin(__builtin_amdgcn_exp2f)
  return __builtin_amdgcn_exp2f(x);
#else
  return exp2f(x);
#endif
}

DEV f32x4 mfma16x16x16_bf16(bf16x4 a, bf16x4 b, f32x4 c) {
#if __has_builtin(__builtin_amdgcn_mfma_f32_16x16x16bf16_1k)
  return __builtin_amdgcn_mfma_f32_16x16x16bf16_1k(a, b, c, 0, 0, 0);
#else
  asm("v_mfma_f32_16x16x16_bf16 %0, %1, %2, %0" : "+v"(c) : "v"(a), "v"(b));
  return c;
#endif
}

DEV void gload_lds16(const void* g, void* l) {
  __builtin_amdgcn_global_load_lds(
      (const __attribute__((address_space(1))) uint32_t*)g,
      (__attribute__((address_space(3))) uint32_t*)l, 16, 0, 0);
}

// ---------------- fused: LN+GELU+encodings (blocks 0..4095) | weight f32->bf16 (blocks 4096..8191) ----------------
__global__ __launch_bounds__(256) void preproc_wconv(const float* x, const float* mul, const float* add,
                                                     const float* lw, const float* lb,
                                                     unsigned short* values, unsigned short* qkin,
                                                     const float* w1, const float* w2,
                                                     unsigned short* o1, unsigned short* o2) {
  int t = threadIdx.x;
  if (blockIdx.x >= 4096) {
    int i = (blockIdx.x - 4096) * 256 + t;   // over f32x4 chunks
    const int n1 = 3145728 / 4;              // in_proj_w chunks
    f32x4 v;
    if (i < n1) v = ((const f32x4*)w1)[i];
    else        v = ((const f32x4*)w2)[i - n1];
    u16x4 r;
#pragma unroll
    for (int j = 0; j < 4; ++j) r[j] = f2bf(v[j]);
    if (i < n1) ((u16x4*)o1)[i] = r;
    else        ((u16x4*)o2)[i - n1] = r;
    return;
  }
  int row = blockIdx.x;                 // 4096 rows
  size_t base = (size_t)row * 1024;
  f32x4 v = ((const f32x4*)(x + base))[t];
  float s  = v[0] + v[1] + v[2] + v[3];
  float s2 = v[0]*v[0] + v[1]*v[1] + v[2]*v[2] + v[3]*v[3];
#pragma unroll
  for (int off = 1; off < 64; off <<= 1) {
    s  += __shfl_xor(s, off);
    s2 += __shfl_xor(s2, off);
  }
  __shared__ float rs[4], rs2[4];
  if ((t & 63) == 0) { rs[t >> 6] = s; rs2[t >> 6] = s2; }
  __syncthreads();
  s  = rs[0] + rs[1] + rs[2] + rs[3];
  s2 = rs2[0] + rs2[1] + rs2[2] + rs2[3];
  float mean = s * 0.0009765625f;
  float var  = s2 * 0.0009765625f - mean * mean;
  float rstd = rsqrtf(var + 1e-5f);
  f32x4 mu = ((const f32x4*)(mul + base))[t];
  f32x4 ad = ((const f32x4*)(add + base))[t];
  f32x4 w4 = ((const f32x4*)lw)[t];
  f32x4 b4 = ((const f32x4*)lb)[t];
  u16x4 vo, qo;
#pragma unroll
  for (int i = 0; i < 4; ++i) {
    float d = (v[i] - mean) * rstd * w4[i] + b4[i];
    float g = 0.5f * d * (1.0f + erff(d * 0.70710678118f));  // exact gelu
    vo[i] = f2bf(g);
    qo[i] = f2bf(g * mu[i] + ad[i]);
  }
  ((u16x4*)(values + base))[t] = vo;
  ((u16x4*)(qkin   + base))[t] = qo;
}

// ---------------- QKV projection GEMM: 64x128 tile, 8 waves, double-buffered, XCD-chunked ----------------
// Q is pre-scaled by 1/sqrt(DH) * log2(e) so attention works in exp2 domain.
#define QSCALE 0.18033688011112042f

DEV void qkv_stage(const unsigned short* A, const unsigned short* W,
                   int m0, int n0, int k0, unsigned short* buf, int t) {
  int w = t >> 6;                        // wave 0..7
  unsigned short* ldsA = buf;
  unsigned short* ldsB = buf + 64 * 64;
  {
    int idx = t;                         // 0..511 chunks of A (64x64)
    int r = idx >> 3;                    // 0..63
    int slot = (idx & 7) ^ (r & 7);
    gload_lds16(A + (size_t)(m0 + r) * 1024 + k0 + slot * 8,
                (char*)ldsA + w * 1024);
  }
#pragma unroll
  for (int i = 0; i < 2; ++i) {
    int idx = i * 512 + t;               // 0..1023 chunks of W (128x64)
    int r = idx >> 3;                    // 0..127
    int slot = (idx & 7) ^ (r & 7);
    gload_lds16(W + (size_t)(n0 + r) * 1024 + k0 + slot * 8,
                (char*)ldsB + i * 8192 + w * 1024);
  }
}

__global__ __launch_bounds__(512) void gemm_qkv(const unsigned short* Aqk, const unsigned short* Av,
                                                const unsigned short* W, const float* bias,
                                                unsigned short* qws, unsigned short* kws,
                                                unsigned short* vtws) {
  __shared__ unsigned short lds[2][(64 + 128) * 64];   // 48 KB double-buffered
  // XCD swizzle: each XCD owns 3 n-tiles (W panels L2-resident) x all 64 m-tiles.
  int id = blockIdx.x;                 // 0..1535
  int xcd = id & 7, rr = id >> 3;      // rr 0..191
  int bx = xcd * 3 + (rr % 3);         // n-tile 0..23
  int by = rr / 3;                     // m-tile 0..63
  int n0 = bx * 128;
  int m0 = by * 64;
  const unsigned short* A = (n0 < 2048) ? Aqk : Av;
  int t = threadIdx.x, lane = t & 63, w = t >> 6;   // w 0..7
  int wr = w & 3, wc = w >> 2;         // wave owns rows wr*16..+15, cols wc*64..+63
  int l15 = lane & 15, l4 = lane >> 4;
  f32x4 z = {0.f, 0.f, 0.f, 0.f};
  f32x4 acc[4];
#pragma unroll
  for (int nn = 0; nn < 4; ++nn) acc[nn] = z;

  qkv_stage(A, W, m0, n0, 0, &lds[0][0], t);
  __syncthreads();

  for (int it = 0; it < 16; ++it) {
    int cur = it & 1;
    if (it < 15) qkv_stage(A, W, m0, n0, (it + 1) * 64, &lds[cur ^ 1][0], t);
    const unsigned short* ldsA = &lds[cur][0];
    const unsigned short* ldsB = &lds[cur][64 * 64];
#pragma unroll
    for (int kk = 0; kk < 2; ++kk) {
      bf16x8 af, bfr[4];
      int kb = kk * 64 + l4 * 16;
      {
        int r = wr * 16 + l15;
        af = *(const bf16x8*)((const char*)ldsA + r * 128 + (kb ^ ((r & 7) << 4)));
      }
#pragma unroll
      for (int nn = 0; nn < 4; ++nn) {
        int r = wc * 64 + nn * 16 + l15;
        bfr[nn] = *(const bf16x8*)((const char*)ldsB + r * 128 + (kb ^ ((r & 7) << 4)));
      }
#pragma unroll
      for (int nn = 0; nn < 4; ++nn)
        acc[nn] = __builtin_amdgcn_mfma_f32_16x16x32_bf16(af, bfr[nn], acc[nn], 0, 0, 0);
    }
    __syncthreads();
  }

  int region = n0 >> 10;                       // block-uniform
  int bb = m0 >> 11, s0 = m0 & 2047;

  if (region == 2) {
    // ---- V: transpose through LDS (64 s x 128 c), then coalesced VT stores ----
    unsigned short* sc = &lds[0][0];
#pragma unroll
    for (int nn = 0; nn < 4; ++nn) {
      int col = wc * 64 + nn * 16 + l15;
      float bs = bias[n0 + col];
#pragma unroll
      for (int reg = 0; reg < 4; ++reg) {
        int row = wr * 16 + l4 * 4 + reg;
        *(unsigned short*)((char*)sc + row * 256 + ((col * 2) ^ ((row & 7) << 4))) =
            f2bf(acc[nn][reg] + bs);
      }
    }
    __syncthreads();
    // thread t: column c = t>>2 (local d), quarter ql = t&3 (16 s each)
    int c = t >> 2, ql = t & 3;
    int e0 = n0 - 2048;
    int h = (e0 + c) >> 6, d = (e0 + c) & 63;
    unsigned short* dst = vtws + ((size_t)(bb * 16 + h) * 64 + d) * 2048 + s0 + ql * 16;
#pragma unroll
    for (int j0 = 0; j0 < 16; j0 += 8) {
      bf16x8 pk;
#pragma unroll
      for (int j = 0; j < 8; ++j) {
        int s = ql * 16 + j0 + j;
        pk[j] = *(const short*)((const char*)sc + s * 256 + ((c * 2) ^ ((s & 7) << 4)));
      }
      *(bf16x8*)(dst + j0) = pk;
    }
  } else {
    // ---- Q/K: direct stores (lane-consecutive d -> coalesced 32B runs) ----
    unsigned short* dst0 = region == 0 ? qws : kws;
    float scl = region == 0 ? QSCALE : 1.0f;
    int row0 = m0 + wr * 16 + l4 * 4;
    int sr = row0 & 2047;
#pragma unroll
    for (int nn = 0; nn < 4; ++nn) {
      int col = n0 + wc * 64 + nn * 16 + l15;
      float bs = bias[col];
      int e = col & 1023;
      int h = e >> 6, d = e & 63;
#pragma unroll
      for (int reg = 0; reg < 4; ++reg)
        dst0[(((size_t)(bb * 16 + h)) * 2048 + sr + reg) * 64 + d] = f2bf((acc[nn][reg] + bs) * scl);
    }
  }
}

// ---------------- flash attention: templated KV block (64 or 32), split-KV across blocks ----------------
template<int KVB>
DEV void stage_kT(const unsigned short* Kp, int kv0, unsigned short* buf, int t) {
  int w = t >> 6;
#pragma unroll
  for (int i = 0; i < KVB / 32; ++i) {
    int idx = i * 256 + t;
    int r = idx >> 3;                    // kv row
    int slot = (idx & 7) ^ (r & 7);
    gload_lds16(Kp + (size_t)(kv0 + r) * 64 + slot * 8,
                (char*)buf + i * 4096 + w * 1024);
  }
}

template<int KVB>
DEV void stage_vtT(const unsigned short* Vt, int kv0, unsigned short* buf, int t) {
  int w = t >> 6;
  constexpr int CPR = KVB / 8;           // 16B chunks per VT row
#pragma unroll
  for (int i = 0; i < KVB / 32; ++i) {
    int idx = i * 256 + t;
    int r = idx / CPR;                   // d row 0..63
    int g = idx % CPR;
    int slot = g ^ (r & (CPR - 1));
    gload_lds16(Vt + (size_t)r * 2048 + kv0 + slot * 8,
                (char*)buf + i * 4096 + w * 1024);
  }
}

template<int KVB>
DEV void attn_computeT(const unsigned short* kbuf, const unsigned short* vtbuf,
                       const bf16x8 (&aq)[2][2], f32x4 (&o)[2][4],
                       float (&m_run)[2], f32x4 (&l_run4)[2], const int (&osrc)[4],
                       int l15, int l4) {
  constexpr int NN = KVB / 16;
  constexpr int RS = KVB * 2;            // VT row stride bytes
  constexpr int VM = (RS >> 4) - 1;      // VT swizzle row mask
  const bf16x4 ones4 = {(short)0x3F80, (short)0x3F80, (short)0x3F80, (short)0x3F80};
  f32x4 z = {0.f, 0.f, 0.f, 0.f};
  f32x4 sc[2][NN];
#pragma unroll
  for (int qs = 0; qs < 2; ++qs)
#pragma unroll
    for (int nn = 0; nn < NN; ++nn) sc[qs][nn] = z;
  __builtin_amdgcn_s_setprio(1);
#pragma unroll
  for (int kk = 0; kk < 2; ++kk) {
#pragma unroll
    for (int nn = 0; nn < NN; ++nn) {
      int r = nn * 16 + l15;
      bf16x8 bk = *(const bf16x8*)((const char*)kbuf + r * 128 + ((kk * 64 + l4 * 16) ^ ((r & 7) << 4)));
#pragma unroll
      for (int qs = 0; qs < 2; ++qs)
        sc[qs][nn] = __builtin_amdgcn_mfma_f32_16x16x32_bf16(bk, aq[qs][kk], sc[qs][nn], 0, 0, 0);
    }
  }
  __builtin_amdgcn_s_setprio(0);

  bf16x4 pa[2][NN];
  float pmax[2];
#pragma unroll
  for (int qs = 0; qs < 2; ++qs) {
    float pm = -1e30f;
#pragma unroll
    for (int nn = 0; nn < NN; ++nn)
      pm = fmaxf(pm, fmaxf(fmaxf(sc[qs][nn][0], sc[qs][nn][1]), fmaxf(sc[qs][nn][2], sc[qs][nn][3])));
    pm = fmaxf(pm, __shfl_xor(pm, 16));
    pm = fmaxf(pm, __shfl_xor(pm, 32));
    pmax[qs] = pm;
  }

  if (__any(fmaxf(pmax[0] - m_run[0], pmax[1] - m_run[1]) > 8.0f)) {
#pragma unroll
    for (int qs = 0; qs < 2; ++qs) {
      float mnew = fmaxf(m_run[qs], pmax[qs]);
      float fs = fast_exp2(m_run[qs] - mnew);
      m_run[qs] = mnew;
      float fo[4];
#pragma unroll
      for (int reg = 0; reg < 4; ++reg) fo[reg] = __shfl(fs, osrc[reg]);
#pragma unroll
      for (int reg = 0; reg < 4; ++reg) l_run4[qs][reg] *= fo[reg];
#pragma unroll
      for (int dt = 0; dt < 4; ++dt)
#pragma unroll
        for (int reg = 0; reg < 4; ++reg) o[qs][dt][reg] *= fo[reg];
    }
  }

#pragma unroll
  for (int qs = 0; qs < 2; ++qs) {
#pragma unroll
    for (int nn = 0; nn < NN; ++nn) {
      float p0 = fast_exp2(sc[qs][nn][0] - m_run[qs]);
      float p1 = fast_exp2(sc[qs][nn][1] - m_run[qs]);
      float p2 = fast_exp2(sc[qs][nn][2] - m_run[qs]);
      float p3 = fast_exp2(sc[qs][nn][3] - m_run[qs]);
      pa[qs][nn][0] = (short)(__float_as_uint(p0) >> 16);
      pa[qs][nn][1] = (short)(__float_as_uint(p1) >> 16);
      pa[qs][nn][2] = (short)(__float_as_uint(p2) >> 16);
      pa[qs][nn][3] = (short)(__float_as_uint(p3) >> 16);
    }
  }

  __builtin_amdgcn_s_setprio(1);
  // l-sum via ones-MFMA: D[q][*] = sum_kv P[q][kv]
#pragma unroll
  for (int nn = 0; nn < NN; ++nn)
#pragma unroll
    for (int qs = 0; qs < 2; ++qs)
      l_run4[qs] = mfma16x16x16_bf16(pa[qs][nn], ones4, l_run4[qs]);
#pragma unroll
  for (int dt = 0; dt < 4; ++dt) {
    int r = dt * 16 + l15;
#pragma unroll
    for (int nn = 0; nn < NN; ++nn) {
      bf16x4 vb = *(const bf16x4*)((const char*)vtbuf + r * RS + ((nn * 32 + l4 * 8) ^ ((r & VM) << 4)));
#pragma unroll
      for (int qs = 0; qs < 2; ++qs)
        o[qs][dt] = mfma16x16x16_bf16(pa[qs][nn], vb, o[qs][dt]);
    }
  }
  __builtin_amdgcn_s_setprio(0);
}

template<int KVB>
__global__ __launch_bounds__(256, 4) void attn_kernel(
    const unsigned short* qws, const unsigned short* kws, const unsigned short* vtws,
    unsigned short* po0, unsigned short* po1, unsigned short* po2, unsigned short* po3,
    float* stats, int nsplit) {
  __shared__ unsigned short ldsK[2][KVB * 64];
  __shared__ unsigned short ldsVT[2][64 * KVB];
  int kvspan = 2048 / nsplit;
  int cpx = 4 * nsplit;                // (32*nsplit combos)/8 XCDs
  int id = blockIdx.x;
  int xcd = id & 7, rr = id >> 3;
  int c = xcd * cpx + (rr % cpx);      // combo 0..32*nsplit-1
  int qt = rr / cpx;                   // 0..15
  int bh = c & 31;
  int qq = c >> 5;                     // split index
  int q0 = qt * 128;
  int kvbase = qq * kvspan;
  int t = threadIdx.x;
  int lane = t & 63, w = t >> 6;
  int l15 = lane & 15, l4 = lane >> 4;

  const unsigned short* Qp = qws + ((size_t)bh * 2048 + q0 + w * 32) * 64;
  const unsigned short* Kp = kws + ((size_t)bh * 2048 + kvbase) * 64;
  const unsigned short* Vt = vtws + (size_t)bh * 64 * 2048 + kvbase;

  bf16x8 aq[2][2];
#pragma unroll
  for (int qs = 0; qs < 2; ++qs)
#pragma unroll
    for (int kk = 0; kk < 2; ++kk)
      aq[qs][kk] = *(const bf16x8*)(Qp + (qs * 16 + l15) * 64 + kk * 32 + l4 * 8);

  f32x4 z = {0.f, 0.f, 0.f, 0.f};
  f32x4 o[2][4];
#pragma unroll
  for (int qs = 0; qs < 2; ++qs)
#pragma unroll
    for (int i = 0; i < 4; ++i) o[qs][i] = z;
  float m_run[2] = {-1e30f, -1e30f};
  f32x4 l_run4[2] = {z, z};

  int osrc[4];
#pragma unroll
  for (int reg = 0; reg < 4; ++reg)
    osrc[reg] = (lane & 48) | (((lane >> 4) & 3) << 2) | reg;

  stage_kT<KVB>(Kp, 0, &ldsK[0][0], t);
  stage_vtT<KVB>(Vt, 0, &ldsVT[0][0], t);
  __syncthreads();

  int iters = kvspan / KVB;
  for (int it = 0; it < iters; ++it) {
    int cur = it & 1;
    if (it < iters - 1) {
      stage_kT<KVB>(Kp, (it + 1) * KVB, &ldsK[cur ^ 1][0], t);
      stage_vtT<KVB>(Vt, (it + 1) * KVB, &ldsVT[cur ^ 1][0], t);
    }
    attn_computeT<KVB>(&ldsK[cur][0], &ldsVT[cur][0], aq, o, m_run, l_run4, osrc, l15, l4);
    __syncthreads();
  }

  unsigned short* po = qq == 0 ? po0 : (qq == 1 ? po1 : (qq == 2 ? po2 : po3));
#pragma unroll
  for (int qs = 0; qs < 2; ++qs) {
#pragma unroll
    for (int reg = 0; reg < 4; ++reg) {
      int qg = q0 + w * 32 + qs * 16 + l4 * 4 + reg;
#pragma unroll
      for (int dt = 0; dt < 4; ++dt) {
        int d = dt * 16 + l15;
        po[((size_t)bh * 2048 + qg) * 64 + d] = f2bf(o[qs][dt][reg]);
      }
    }
  }
  if (l4 == 0) {
#pragma unroll
    for (int qs = 0; qs < 2; ++qs) {
      int qg = q0 + w * 32 + qs * 16 + l15;
      size_t si = (((size_t)qq * 32 + bh) * 2048 + qg) * 2;
      stats[si] = m_run[qs];
    }
  }
  if (l15 == 0) {
#pragma unroll
    for (int qs = 0; qs < 2; ++qs) {
#pragma unroll
      for (int reg = 0; reg < 4; ++reg) {
        int qg = q0 + w * 32 + qs * 16 + l4 * 4 + reg;
        size_t si = (((size_t)qq * 32 + bh) * 2048 + qg) * 2;
        stats[si + 1] = l_run4[qs][reg];
      }
    }
  }
}

// ---------------- merge the KV-split partials ----------------
template<int NSPLIT>
__global__ __launch_bounds__(256) void attn_merge(const unsigned short* po0, const unsigned short* po1,
                                                  const unsigned short* po2, const unsigned short* po3,
                                                  const float* stats, unsigned short* attnb) {
  int row = blockIdx.x;            // 4096 = b*2048 + q
  int b = row >> 11, q = row & 2047;
  int t = threadIdx.x;
  int c0 = t * 4;
  int h = c0 >> 6, d = c0 & 63;
  int bh = b * 16 + h;
  float ms[NSPLIT], ls[NSPLIT];
  float m = -1e30f;
#pragma unroll
  for (int s = 0; s < NSPLIT; ++s) {
    size_t si = (((size_t)s * 32 + bh) * 2048 + q) * 2;
    ms[s] = stats[si];
    ls[s] = stats[si + 1];
    m = fmaxf(m, ms[s]);
  }
  float a[NSPLIT];
  float denom = 0.f;
#pragma unroll
  for (int s = 0; s < NSPLIT; ++s) {
    a[s] = fast_exp2(ms[s] - m);
    denom += ls[s] * a[s];
  }
  float inv = 1.0f / denom;
#pragma unroll
  for (int s = 0; s < NSPLIT; ++s) a[s] *= inv;
  size_t off = ((size_t)bh * 2048 + q) * 64 + d;
  const unsigned short* pos[4] = {po0, po1, po2, po3};
  float acc[4] = {0.f, 0.f, 0.f, 0.f};
#pragma unroll
  for (int s = 0; s < NSPLIT; ++s) {
    u16x4 x = *(const u16x4*)(pos[s] + off);
#pragma unroll
    for (int j = 0; j < 4; ++j) acc[j] += bf2f((unsigned short)x[j]) * a[s];
  }
  u16x4 r;
#pragma unroll
  for (int j = 0; j < 4; ++j) r[j] = f2bf(acc[j]);
  *(u16x4*)(attnb + (size_t)row * 1024 + c0) = r;
}

// ---------------- out projection + bias + residual (64x64 tile, 4 blocks/CU, XCD-chunked) ----------------
__global__ __launch_bounds__(256) void gemm_out(const unsigned short* A, const unsigned short* W,
                                                const float* bias, const float* resid, float* out) {
  __shared__ unsigned short ldsA[64 * 64];
  __shared__ unsigned short ldsB[64 * 64];
  // XCD swizzle: each XCD owns 2 n-tiles (W panels L2-resident) x all 64 m-tiles.
  int id = blockIdx.x;                 // 0..1023
  int xcd = id & 7, rr = id >> 3;      // rr 0..127
  int bx = xcd * 2 + (rr & 1);         // n-tile 0..15
  int by = rr >> 1;                    // m-tile 0..63
  int n0 = bx * 64;
  int m0 = by * 64;
  int t = threadIdx.x;
  int lane = t & 63;
  int w = t >> 6;              // wave handles rows w*16..+15, all 64 cols
  int l15 = lane & 15, l4 = lane >> 4;
  f32x4 z = {0.f, 0.f, 0.f, 0.f};
  f32x4 acc[4];
#pragma unroll
  for (int nn = 0; nn < 4; ++nn) acc[nn] = z;

  for (int k0 = 0; k0 < 1024; k0 += 64) {
#pragma unroll
    for (int i = 0; i < 2; ++i) {
      int idx = i * 256 + t;
      int r = idx >> 3;
      int slot = (idx & 7) ^ (r & 7);
      gload_lds16(A + (size_t)(m0 + r) * 1024 + k0 + slot * 8,
                  (char*)ldsA + i * 4096 + w * 1024);
    }
#pragma unroll
    for (int i = 0; i < 2; ++i) {
      int idx = i * 256 + t;
      int r = idx >> 3;
      int slot = (idx & 7) ^ (r & 7);
      gload_lds16(W + (size_t)(n0 + r) * 1024 + k0 + slot * 8,
                  (char*)ldsB + i * 4096 + w * 1024);
    }
    __syncthreads();
#pragma unroll
    for (int kk = 0; kk < 2; ++kk) {
      bf16x8 af, bfr[4];
      int kb = kk * 64 + l4 * 16;
      {
        int r = w * 16 + l15;
        af = *(const bf16x8*)((const char*)ldsA + r * 128 + (kb ^ ((r & 7) << 4)));
      }
#pragma unroll
      for (int nn = 0; nn < 4; ++nn) {
        int r = nn * 16 + l15;
        bfr[nn] = *(const bf16x8*)((const char*)ldsB + r * 128 + (kb ^ ((r & 7) << 4)));
      }
#pragma unroll
      for (int nn = 0; nn < 4; ++nn)
        acc[nn] = __builtin_amdgcn_mfma_f32_16x16x32_bf16(af, bfr[nn], acc[nn], 0, 0, 0);
    }
    __syncthreads();
  }

#pragma unroll
  for (int nn = 0; nn < 4; ++nn) {
    int col = n0 + nn * 16 + l15;
    float bs = bias[col];
#pragma unroll
    for (int reg = 0; reg < 4; ++reg) {
      int r = m0 + w * 16 + l4 * 4 + reg;
      size_t off = (size_t)r * 1024 + col;
      out[off] = acc[nn][reg] + bs + resid[off];
    }
  }
}

extern "C" void kernel_launch(void* const* d_in, const int* in_sizes, int n_in,
                              void* d_out, int out_size, void* d_ws, size_t ws_size,
                              hipStream_t stream) {
  const float* in_feats   = (const float*)d_in[0];
  const float* mul_encs   = (const float*)d_in[1];
  const float* add_encs   = (const float*)d_in[2];
  const float* ln_w       = (const float*)d_in[3];
  const float* ln_b       = (const float*)d_in[4];
  const float* in_proj_w  = (const float*)d_in[5];
  const float* in_proj_b  = (const float*)d_in[6];
  const float* out_proj_w = (const float*)d_in[7];
  const float* out_proj_b = (const float*)d_in[8];
  float* out = (float*)d_out;

  unsigned short* ws = (unsigned short*)d_ws;
  unsigned short* values = ws;
  unsigned short* qkin   = values + 4194304;
  unsigned short* wqkv   = qkin + 4194304;
  unsigned short* wout   = wqkv + 3145728;
  unsigned short* qws    = wout + 1048576;
  unsigned short* kws    = qws + 4194304;
  unsigned short* vtws   = kws + 4194304;
  unsigned short* attnb  = vtws + 4194304;   // ends at 29,360,128 ushorts

  // dead-after-gemm_qkv regions reused by attention partials:
  unsigned short* po0   = values;            // 8MB
  unsigned short* po1   = qkin;              // 8MB
  float*          stats = (float*)wqkv;      // up to 2MB (fits in 6MB)

  // 4-way split needs two extra 8MB partial buffers beyond the 56MB base layout.
  bool four = ws_size >= 75497472ull;        // 37,748,736 ushorts * 2B
  unsigned short* po2 = four ? (attnb + 4194304) : po0;   // dummy when unused
  unsigned short* po3 = four ? (attnb + 8388608) : po1;

  preproc_wconv<<<8192, 256, 0, stream>>>(in_feats, mul_encs, add_encs, ln_w, ln_b,
                                          values, qkin, in_proj_w, out_proj_w, wqkv, wout);
  gemm_qkv<<<1536, 512, 0, stream>>>(qkin, values, wqkv, in_proj_b, qws, kws, vtws);
  if (four) {
    attn_kernel<32><<<2048, 256, 0, stream>>>(qws, kws, vtws, po0, po1, po2, po3, stats, 4);
    attn_merge<4><<<4096, 256, 0, stream>>>(po0, po1, po2, po3, stats, attnb);
  } else {
    attn_kernel<64><<<1024, 256, 0, stream>>>(qws, kws, vtws, po0, po1, po2, po3, stats, 2);
    attn_merge<2><<<4096, 256, 0, stream>>>(po0, po1, po2, po3, stats, attnb);
  }
  gemm_out<<<1024, 256, 0, stream>>>(attnb, wout, out_proj_b, in_feats, out);
}

// Round 19
// 129.852 us; speedup vs baseline: 3.4983x; 1.0883x over previous
//
#include <hip/hip_runtime.h>
#include <stdint.h>

// B=2 S=2048 E=1024 H=16 DH=64.  M = B*S = 4096.
// ws layout (ushort elems): values 4M | qkin 4M | wqkv 3M | wout 1M | q 4M | k 4M | vt 4M | attn 4M
// vt layout: [bh][d=64][s=2048]  (V transposed, written coalesced via LDS in gemm_qkv epilogue)
// After gemm_qkv, values/qkin/wqkv are dead -> reused as attn partials: po0=values, po1=qkin, stats=wqkv.

typedef __attribute__((ext_vector_type(8))) short bf16x8;
typedef __attribute__((ext_vector_type(4))) short bf16x4;
typedef __attribute__((ext_vector_type(4))) float f32x4;
typedef __attribute__((ext_vector_type(4))) unsigned short u16x4;

#define DEV __device__ __forceinline__

DEV unsigned short f2bf(float f) {
  uint32_t u = __float_as_uint(f);
  u += 0x7fff + ((u >> 16) & 1);
  return (unsigned short)(u >> 16);
}

DEV float fast_exp2(float x) {
#if __has_builtin(__builtin_amdgcn_exp2f)
  return __builtin_amdgcn_exp2f(x);
#else
  return exp2f(x);
#endif
}

DEV f32x4 mfma16x16x16_bf16(bf16x4 a, bf16x4 b, f32x4 c) {
#if __has_builtin(__builtin_amdgcn_mfma_f32_16x16x16bf16_1k)
  return __builtin_amdgcn_mfma_f32_16x16x16bf16_1k(a, b, c, 0, 0, 0);
#else
  asm("v_mfma_f32_16x16x16_bf16 %0, %1, %2, %0" : "+v"(c) : "v"(a), "v"(b));
  return c;
#endif
}

DEV void gload_lds16(const void* g, void* l) {
  __builtin_amdgcn_global_load_lds(
      (const __attribute__((address_space(1))) uint32_t*)g,
      (__attribute__((address_space(3))) uint32_t*)l, 16, 0, 0);
}

// ---------------- fused: LN+GELU+encodings (blocks 0..4095) | weight f32->bf16 (blocks 4096..8191) ----------------
__global__ __launch_bounds__(256) void preproc_wconv(const float* x, const float* mul, const float* add,
                                                     const float* lw, const float* lb,
                                                     unsigned short* values, unsigned short* qkin,
                                                     const float* w1, const float* w2,
                                                     unsigned short* o1, unsigned short* o2) {
  int t = threadIdx.x;
  if (blockIdx.x >= 4096) {
    int i = (blockIdx.x - 4096) * 256 + t;   // over f32x4 chunks
    const int n1 = 3145728 / 4;              // in_proj_w chunks
    f32x4 v;
    if (i < n1) v = ((const f32x4*)w1)[i];
    else        v = ((const f32x4*)w2)[i - n1];
    u16x4 r;
#pragma unroll
    for (int j = 0; j < 4; ++j) r[j] = f2bf(v[j]);
    if (i < n1) ((u16x4*)o1)[i] = r;
    else        ((u16x4*)o2)[i - n1] = r;
    return;
  }
  int row = blockIdx.x;                 // 4096 rows
  size_t base = (size_t)row * 1024;
  f32x4 v = ((const f32x4*)(x + base))[t];
  float s  = v[0] + v[1] + v[2] + v[3];
  float s2 = v[0]*v[0] + v[1]*v[1] + v[2]*v[2] + v[3]*v[3];
#pragma unroll
  for (int off = 1; off < 64; off <<= 1) {
    s  += __shfl_xor(s, off);
    s2 += __shfl_xor(s2, off);
  }
  __shared__ float rs[4], rs2[4];
  if ((t & 63) == 0) { rs[t >> 6] = s; rs2[t >> 6] = s2; }
  __syncthreads();
  s  = rs[0] + rs[1] + rs[2] + rs[3];
  s2 = rs2[0] + rs2[1] + rs2[2] + rs2[3];
  float mean = s * 0.0009765625f;
  float var  = s2 * 0.0009765625f - mean * mean;
  float rstd = rsqrtf(var + 1e-5f);
  f32x4 mu = ((const f32x4*)(mul + base))[t];
  f32x4 ad = ((const f32x4*)(add + base))[t];
  f32x4 w4 = ((const f32x4*)lw)[t];
  f32x4 b4 = ((const f32x4*)lb)[t];
  u16x4 vo, qo;
#pragma unroll
  for (int i = 0; i < 4; ++i) {
    float d = (v[i] - mean) * rstd * w4[i] + b4[i];
    float g = 0.5f * d * (1.0f + erff(d * 0.70710678118f));  // exact gelu
    vo[i] = f2bf(g);
    qo[i] = f2bf(g * mu[i] + ad[i]);
  }
  ((u16x4*)(values + base))[t] = vo;
  ((u16x4*)(qkin   + base))[t] = qo;
}

// ---------------- QKV projection GEMM: 64x128 tile, 8 waves, double-buffered, XCD-chunked ----------------
// Q is pre-scaled by 1/sqrt(DH) * log2(e) so attention works in exp2 domain.
#define QSCALE 0.18033688011112042f

DEV void qkv_stage(const unsigned short* A, const unsigned short* W,
                   int m0, int n0, int k0, unsigned short* buf, int t) {
  int w = t >> 6;                        // wave 0..7
  unsigned short* ldsA = buf;
  unsigned short* ldsB = buf + 64 * 64;
  {
    int idx = t;                         // 0..511 chunks of A (64x64)
    int r = idx >> 3;                    // 0..63
    int slot = (idx & 7) ^ (r & 7);
    gload_lds16(A + (size_t)(m0 + r) * 1024 + k0 + slot * 8,
                (char*)ldsA + w * 1024);
  }
#pragma unroll
  for (int i = 0; i < 2; ++i) {
    int idx = i * 512 + t;               // 0..1023 chunks of W (128x64)
    int r = idx >> 3;                    // 0..127
    int slot = (idx & 7) ^ (r & 7);
    gload_lds16(W + (size_t)(n0 + r) * 1024 + k0 + slot * 8,
                (char*)ldsB + i * 8192 + w * 1024);
  }
}

__global__ __launch_bounds__(512) void gemm_qkv(const unsigned short* Aqk, const unsigned short* Av,
                                                const unsigned short* W, const float* bias,
                                                unsigned short* qws, unsigned short* kws,
                                                unsigned short* vtws) {
  __shared__ unsigned short lds[2][(64 + 128) * 64];   // 48 KB double-buffered
  // XCD swizzle: each XCD owns 3 n-tiles (W panels L2-resident) x all 64 m-tiles.
  int id = blockIdx.x;                 // 0..1535
  int xcd = id & 7, rr = id >> 3;      // rr 0..191
  int bx = xcd * 3 + (rr % 3);         // n-tile 0..23
  int by = rr / 3;                     // m-tile 0..63
  int n0 = bx * 128;
  int m0 = by * 64;
  const unsigned short* A = (n0 < 2048) ? Aqk : Av;
  int t = threadIdx.x, lane = t & 63, w = t >> 6;   // w 0..7
  int wr = w & 3, wc = w >> 2;         // wave owns rows wr*16..+15, cols wc*64..+63
  int l15 = lane & 15, l4 = lane >> 4;
  f32x4 z = {0.f, 0.f, 0.f, 0.f};
  f32x4 acc[4];
#pragma unroll
  for (int nn = 0; nn < 4; ++nn) acc[nn] = z;

  qkv_stage(A, W, m0, n0, 0, &lds[0][0], t);
  __syncthreads();

  for (int it = 0; it < 16; ++it) {
    int cur = it & 1;
    if (it < 15) qkv_stage(A, W, m0, n0, (it + 1) * 64, &lds[cur ^ 1][0], t);
    const unsigned short* ldsA = &lds[cur][0];
    const unsigned short* ldsB = &lds[cur][64 * 64];
#pragma unroll
    for (int kk = 0; kk < 2; ++kk) {
      bf16x8 af, bfr[4];
      int kb = kk * 64 + l4 * 16;
      {
        int r = wr * 16 + l15;
        af = *(const bf16x8*)((const char*)ldsA + r * 128 + (kb ^ ((r & 7) << 4)));
      }
#pragma unroll
      for (int nn = 0; nn < 4; ++nn) {
        int r = wc * 64 + nn * 16 + l15;
        bfr[nn] = *(const bf16x8*)((const char*)ldsB + r * 128 + (kb ^ ((r & 7) << 4)));
      }
#pragma unroll
      for (int nn = 0; nn < 4; ++nn)
        acc[nn] = __builtin_amdgcn_mfma_f32_16x16x32_bf16(af, bfr[nn], acc[nn], 0, 0, 0);
    }
    __syncthreads();
  }

  int region = n0 >> 10;                       // block-uniform
  int bb = m0 >> 11, s0 = m0 & 2047;

  if (region == 2) {
    // ---- V: transpose through LDS (64 s x 128 c), then coalesced VT stores ----
    unsigned short* sc = &lds[0][0];
#pragma unroll
    for (int nn = 0; nn < 4; ++nn) {
      int col = wc * 64 + nn * 16 + l15;
      float bs = bias[n0 + col];
#pragma unroll
      for (int reg = 0; reg < 4; ++reg) {
        int row = wr * 16 + l4 * 4 + reg;
        *(unsigned short*)((char*)sc + row * 256 + ((col * 2) ^ ((row & 7) << 4))) =
            f2bf(acc[nn][reg] + bs);
      }
    }
    __syncthreads();
    // thread t: column c = t>>2 (local d), quarter ql = t&3 (16 s each)
    int c = t >> 2, ql = t & 3;
    int e0 = n0 - 2048;
    int h = (e0 + c) >> 6, d = (e0 + c) & 63;
    unsigned short* dst = vtws + ((size_t)(bb * 16 + h) * 64 + d) * 2048 + s0 + ql * 16;
#pragma unroll
    for (int j0 = 0; j0 < 16; j0 += 8) {
      bf16x8 pk;
#pragma unroll
      for (int j = 0; j < 8; ++j) {
        int s = ql * 16 + j0 + j;
        pk[j] = *(const short*)((const char*)sc + s * 256 + ((c * 2) ^ ((s & 7) << 4)));
      }
      *(bf16x8*)(dst + j0) = pk;
    }
  } else {
    // ---- Q/K: direct stores (lane-consecutive d -> coalesced 32B runs) ----
    unsigned short* dst0 = region == 0 ? qws : kws;
    float scl = region == 0 ? QSCALE : 1.0f;
    int row0 = m0 + wr * 16 + l4 * 4;
    int sr = row0 & 2047;
#pragma unroll
    for (int nn = 0; nn < 4; ++nn) {
      int col = n0 + wc * 64 + nn * 16 + l15;
      float bs = bias[col];
      int e = col & 1023;
      int h = e >> 6, d = e & 63;
#pragma unroll
      for (int reg = 0; reg < 4; ++reg)
        dst0[(((size_t)(bb * 16 + h)) * 2048 + sr + reg) * 64 + d] = f2bf((acc[nn][reg] + bs) * scl);
    }
  }
}

// ---------------- flash attention: split-KV across blocks, LDS dbuf, 32 q/wave ----------------
DEV void stage_k(const unsigned short* Kp, int kv0, unsigned short* buf, int t) {
  int w = t >> 6;
#pragma unroll
  for (int i = 0; i < 2; ++i) {
    int idx = i * 256 + t;
    int r = idx >> 3;
    int slot = (idx & 7) ^ (r & 7);
    gload_lds16(Kp + (size_t)(kv0 + r) * 64 + slot * 8,
                (char*)buf + i * 4096 + w * 1024);
  }
}

DEV void stage_vt(const unsigned short* Vt, int kv0, unsigned short* buf, int t) {
  int w = t >> 6;
#pragma unroll
  for (int i = 0; i < 2; ++i) {
    int idx = i * 256 + t;
    int r = idx >> 3;                        // d row 0..63
    int slot = (idx & 7) ^ (r & 7);
    gload_lds16(Vt + (size_t)r * 2048 + kv0 + slot * 8,
                (char*)buf + i * 4096 + w * 1024);
  }
}

DEV void attn_compute(const unsigned short* kbuf, const unsigned short* vtbuf,
                      const bf16x8 (&aq)[2][2], f32x4 (&o)[2][4],
                      float (&m_run)[2], f32x4 (&l_run4)[2], const int (&osrc)[4],
                      int l15, int l4) {
  const bf16x4 ones4 = {(short)0x3F80, (short)0x3F80, (short)0x3F80, (short)0x3F80};
  f32x4 z = {0.f, 0.f, 0.f, 0.f};
  f32x4 sc[2][4];
#pragma unroll
  for (int qs = 0; qs < 2; ++qs)
#pragma unroll
    for (int nn = 0; nn < 4; ++nn) sc[qs][nn] = z;
  __builtin_amdgcn_s_setprio(1);
#pragma unroll
  for (int kk = 0; kk < 2; ++kk) {
#pragma unroll
    for (int nn = 0; nn < 4; ++nn) {
      int r = nn * 16 + l15;
      bf16x8 bk = *(const bf16x8*)((const char*)kbuf + r * 128 + ((kk * 64 + l4 * 16) ^ ((r & 7) << 4)));
#pragma unroll
      for (int qs = 0; qs < 2; ++qs)
        sc[qs][nn] = __builtin_amdgcn_mfma_f32_16x16x32_bf16(bk, aq[qs][kk], sc[qs][nn], 0, 0, 0);
    }
  }
  __builtin_amdgcn_s_setprio(0);

  bf16x4 pa[2][4];
  float pmax[2];
#pragma unroll
  for (int qs = 0; qs < 2; ++qs) {
    float mA = fmaxf(fmaxf(sc[qs][0][0], sc[qs][0][1]), fmaxf(sc[qs][0][2], sc[qs][0][3]));
    float mB = fmaxf(fmaxf(sc[qs][1][0], sc[qs][1][1]), fmaxf(sc[qs][1][2], sc[qs][1][3]));
    float mC = fmaxf(fmaxf(sc[qs][2][0], sc[qs][2][1]), fmaxf(sc[qs][2][2], sc[qs][2][3]));
    float mD = fmaxf(fmaxf(sc[qs][3][0], sc[qs][3][1]), fmaxf(sc[qs][3][2], sc[qs][3][3]));
    float pm = fmaxf(fmaxf(mA, mB), fmaxf(mC, mD));
    pm = fmaxf(pm, __shfl_xor(pm, 16));
    pm = fmaxf(pm, __shfl_xor(pm, 32));
    pmax[qs] = pm;
  }

  if (__any(fmaxf(pmax[0] - m_run[0], pmax[1] - m_run[1]) > 8.0f)) {
#pragma unroll
    for (int qs = 0; qs < 2; ++qs) {
      float mnew = fmaxf(m_run[qs], pmax[qs]);
      float fs = fast_exp2(m_run[qs] - mnew);
      m_run[qs] = mnew;
      float fo[4];
#pragma unroll
      for (int reg = 0; reg < 4; ++reg) fo[reg] = __shfl(fs, osrc[reg]);
#pragma unroll
      for (int reg = 0; reg < 4; ++reg) l_run4[qs][reg] *= fo[reg];
#pragma unroll
      for (int dt = 0; dt < 4; ++dt)
#pragma unroll
        for (int reg = 0; reg < 4; ++reg) o[qs][dt][reg] *= fo[reg];
    }
  }

#pragma unroll
  for (int qs = 0; qs < 2; ++qs) {
#pragma unroll
    for (int nn = 0; nn < 4; ++nn) {
      float p0 = fast_exp2(sc[qs][nn][0] - m_run[qs]);
      float p1 = fast_exp2(sc[qs][nn][1] - m_run[qs]);
      float p2 = fast_exp2(sc[qs][nn][2] - m_run[qs]);
      float p3 = fast_exp2(sc[qs][nn][3] - m_run[qs]);
      pa[qs][nn][0] = (short)(__float_as_uint(p0) >> 16);
      pa[qs][nn][1] = (short)(__float_as_uint(p1) >> 16);
      pa[qs][nn][2] = (short)(__float_as_uint(p2) >> 16);
      pa[qs][nn][3] = (short)(__float_as_uint(p3) >> 16);
    }
  }

  __builtin_amdgcn_s_setprio(1);
  // l-sum via ones-MFMA: D[q][*] = sum_kv P[q][kv], replicated across l15; row q = l4*4+reg
#pragma unroll
  for (int nn = 0; nn < 4; ++nn)
#pragma unroll
    for (int qs = 0; qs < 2; ++qs)
      l_run4[qs] = mfma16x16x16_bf16(pa[qs][nn], ones4, l_run4[qs]);
#pragma unroll
  for (int dt = 0; dt < 4; ++dt) {
    int r = dt * 16 + l15;
#pragma unroll
    for (int nn = 0; nn < 4; ++nn) {
      bf16x4 vb = *(const bf16x4*)((const char*)vtbuf + r * 128 + ((nn * 32 + l4 * 8) ^ ((r & 7) << 4)));
#pragma unroll
      for (int qs = 0; qs < 2; ++qs)
        o[qs][dt] = mfma16x16x16_bf16(pa[qs][nn], vb, o[qs][dt]);
    }
  }
  __builtin_amdgcn_s_setprio(0);
}

__global__ __launch_bounds__(256, 4) void attn_kernel(const unsigned short* qws, const unsigned short* kws,
                                                      const unsigned short* vtws,
                                                      unsigned short* po0, unsigned short* po1,
                                                      float* stats) {
  // XCD swizzle: each XCD owns 8 (bh,half) combos (2 MB of KV, L2-resident) x all 16 q-tiles.
  int id = blockIdx.x;                 // 0..1023
  int xcd = id & 7, rr = id >> 3;      // rr 0..127
  int c = xcd * 8 + (rr & 7);          // combo 0..63
  int qt = rr >> 3;                    // 0..15
  int bh = c & 31;
  int half = c >> 5;
  int q0 = qt * 128;
  int kvbase = half * 1024;
  int t = threadIdx.x;
  int lane = t & 63, w = t >> 6;
  int l15 = lane & 15, l4 = lane >> 4;
  __shared__ unsigned short ldsK[2][64 * 64];
  __shared__ unsigned short ldsVT[2][64 * 64];

  const unsigned short* Qp = qws + ((size_t)bh * 2048 + q0 + w * 32) * 64;
  const unsigned short* Kp = kws + ((size_t)bh * 2048 + kvbase) * 64;
  const unsigned short* Vt = vtws + (size_t)bh * 64 * 2048 + kvbase;

  // Q fragments (B-operand of swapped QK): lane holds Q[q = qs*16+l15][d = kk*32 + l4*8 .. +7]
  bf16x8 aq[2][2];
#pragma unroll
  for (int qs = 0; qs < 2; ++qs)
#pragma unroll
    for (int kk = 0; kk < 2; ++kk)
      aq[qs][kk] = *(const bf16x8*)(Qp + (qs * 16 + l15) * 64 + kk * 32 + l4 * 8);

  f32x4 z = {0.f, 0.f, 0.f, 0.f};
  f32x4 o[2][4];
#pragma unroll
  for (int qs = 0; qs < 2; ++qs)
#pragma unroll
    for (int i = 0; i < 4; ++i) o[qs][i] = z;
  float m_run[2] = {-1e30f, -1e30f};
  f32x4 l_run4[2] = {z, z};

  int osrc[4];
#pragma unroll
  for (int reg = 0; reg < 4; ++reg)
    osrc[reg] = (lane & 48) | (((lane >> 4) & 3) << 2) | reg;

  // prologue: stage tile 0
  stage_k(Kp, 0, &ldsK[0][0], t);
  stage_vt(Vt, 0, &ldsVT[0][0], t);
  __syncthreads();

  for (int it = 0; it < 16; ++it) {
    int cur = it & 1;
    if (it < 15) {
      stage_k(Kp, (it + 1) * 64, &ldsK[cur ^ 1][0], t);
      stage_vt(Vt, (it + 1) * 64, &ldsVT[cur ^ 1][0], t);
    }
    attn_compute(&ldsK[cur][0], &ldsVT[cur][0], aq, o, m_run, l_run4, osrc, l15, l4);
    __syncthreads();
  }

  // epilogue: store unnormalized partial O (bf16) + stats (m,l) f32
  unsigned short* po = half ? po1 : po0;
#pragma unroll
  for (int qs = 0; qs < 2; ++qs) {
#pragma unroll
    for (int reg = 0; reg < 4; ++reg) {
      int qg = q0 + w * 32 + qs * 16 + l4 * 4 + reg;
#pragma unroll
      for (int dt = 0; dt < 4; ++dt) {
        int d = dt * 16 + l15;
        po[((size_t)bh * 2048 + qg) * 64 + d] = f2bf(o[qs][dt][reg]);
      }
    }
  }
  if (l4 == 0) {
#pragma unroll
    for (int qs = 0; qs < 2; ++qs) {
      int qg = q0 + w * 32 + qs * 16 + l15;
      size_t si = (((size_t)half * 32 + bh) * 2048 + qg) * 2;
      stats[si] = m_run[qs];
    }
  }
  if (l15 == 0) {
#pragma unroll
    for (int qs = 0; qs < 2; ++qs) {
#pragma unroll
      for (int reg = 0; reg < 4; ++reg) {
        int qg = q0 + w * 32 + qs * 16 + l4 * 4 + reg;
        size_t si = (((size_t)half * 32 + bh) * 2048 + qg) * 2;
        stats[si + 1] = l_run4[qs][reg];
      }
    }
  }
}

// ---------------- merge the two KV-half partials ----------------
__global__ __launch_bounds__(256) void attn_merge(const unsigned short* po0, const unsigned short* po1,
                                                  const float* stats, unsigned short* attnb) {
  int row = blockIdx.x;            // 4096 = b*2048 + q
  int b = row >> 11, q = row & 2047;
  int t = threadIdx.x;
  int c0 = t * 4;
  int h = c0 >> 6, d = c0 & 63;
  int bh = b * 16 + h;
  size_t si0 = ((size_t)bh * 2048 + q) * 2;
  size_t si1 = (((size_t)32 + bh) * 2048 + q) * 2;
  float m0 = stats[si0], l0 = stats[si0 + 1];
  float m1 = stats[si1], l1 = stats[si1 + 1];
  float m = fmaxf(m0, m1);
  float f0 = fast_exp2(m0 - m), f1 = fast_exp2(m1 - m);
  float inv = 1.0f / (l0 * f0 + l1 * f1);
  float a0 = f0 * inv, a1 = f1 * inv;
  size_t off = ((size_t)bh * 2048 + q) * 64 + d;
  u16x4 x0 = *(const u16x4*)(po0 + off);
  u16x4 x1 = *(const u16x4*)(po1 + off);
  u16x4 r;
#pragma unroll
  for (int j = 0; j < 4; ++j) {
    float v0 = __uint_as_float((uint32_t)x0[j] << 16);
    float v1 = __uint_as_float((uint32_t)x1[j] << 16);
    r[j] = f2bf(v0 * a0 + v1 * a1);
  }
  *(u16x4*)(attnb + (size_t)row * 1024 + c0) = r;
}

// ---------------- out projection + bias + residual (64x64 tile, 4 blocks/CU, XCD-chunked) ----------------
__global__ __launch_bounds__(256) void gemm_out(const unsigned short* A, const unsigned short* W,
                                                const float* bias, const float* resid, float* out) {
  __shared__ unsigned short ldsA[64 * 64];
  __shared__ unsigned short ldsB[64 * 64];
  // XCD swizzle: each XCD owns 2 n-tiles (W panels L2-resident) x all 64 m-tiles.
  int id = blockIdx.x;                 // 0..1023
  int xcd = id & 7, rr = id >> 3;      // rr 0..127
  int bx = xcd * 2 + (rr & 1);         // n-tile 0..15
  int by = rr >> 1;                    // m-tile 0..63
  int n0 = bx * 64;
  int m0 = by * 64;
  int t = threadIdx.x;
  int lane = t & 63;
  int w = t >> 6;              // wave handles rows w*16..+15, all 64 cols
  int l15 = lane & 15, l4 = lane >> 4;
  f32x4 z = {0.f, 0.f, 0.f, 0.f};
  f32x4 acc[4];
#pragma unroll
  for (int nn = 0; nn < 4; ++nn) acc[nn] = z;

  for (int k0 = 0; k0 < 1024; k0 += 64) {
#pragma unroll
    for (int i = 0; i < 2; ++i) {
      int idx = i * 256 + t;
      int r = idx >> 3;
      int slot = (idx & 7) ^ (r & 7);
      gload_lds16(A + (size_t)(m0 + r) * 1024 + k0 + slot * 8,
                  (char*)ldsA + i * 4096 + w * 1024);
    }
#pragma unroll
    for (int i = 0; i < 2; ++i) {
      int idx = i * 256 + t;
      int r = idx >> 3;
      int slot = (idx & 7) ^ (r & 7);
      gload_lds16(W + (size_t)(n0 + r) * 1024 + k0 + slot * 8,
                  (char*)ldsB + i * 4096 + w * 1024);
    }
    __syncthreads();
#pragma unroll
    for (int kk = 0; kk < 2; ++kk) {
      bf16x8 af, bfr[4];
      int kb = kk * 64 + l4 * 16;
      {
        int r = w * 16 + l15;
        af = *(const bf16x8*)((const char*)ldsA + r * 128 + (kb ^ ((r & 7) << 4)));
      }
#pragma unroll
      for (int nn = 0; nn < 4; ++nn) {
        int r = nn * 16 + l15;
        bfr[nn] = *(const bf16x8*)((const char*)ldsB + r * 128 + (kb ^ ((r & 7) << 4)));
      }
#pragma unroll
      for (int nn = 0; nn < 4; ++nn)
        acc[nn] = __builtin_amdgcn_mfma_f32_16x16x32_bf16(af, bfr[nn], acc[nn], 0, 0, 0);
    }
    __syncthreads();
  }

#pragma unroll
  for (int nn = 0; nn < 4; ++nn) {
    int col = n0 + nn * 16 + l15;
    float bs = bias[col];
#pragma unroll
    for (int reg = 0; reg < 4; ++reg) {
      int r = m0 + w * 16 + l4 * 4 + reg;
      size_t off = (size_t)r * 1024 + col;
      out[off] = acc[nn][reg] + bs + resid[off];
    }
  }
}

extern "C" void kernel_launch(void* const* d_in, const int* in_sizes, int n_in,
                              void* d_out, int out_size, void* d_ws, size_t ws_size,
                              hipStream_t stream) {
  const float* in_feats   = (const float*)d_in[0];
  const float* mul_encs   = (const float*)d_in[1];
  const float* add_encs   = (const float*)d_in[2];
  const float* ln_w       = (const float*)d_in[3];
  const float* ln_b       = (const float*)d_in[4];
  const float* in_proj_w  = (const float*)d_in[5];
  const float* in_proj_b  = (const float*)d_in[6];
  const float* out_proj_w = (const float*)d_in[7];
  const float* out_proj_b = (const float*)d_in[8];
  float* out = (float*)d_out;

  unsigned short* ws = (unsigned short*)d_ws;
  unsigned short* values = ws;
  unsigned short* qkin   = values + 4194304;
  unsigned short* wqkv   = qkin + 4194304;
  unsigned short* wout   = wqkv + 3145728;
  unsigned short* qws    = wout + 1048576;
  unsigned short* kws    = qws + 4194304;
  unsigned short* vtws   = kws + 4194304;
  unsigned short* attnb  = vtws + 4194304;

  // dead-after-gemm_qkv regions reused by attention partials:
  unsigned short* po0   = values;          // 4M ushorts = 8MB
  unsigned short* po1   = qkin;            // 4M ushorts = 8MB
  float*          stats = (float*)wqkv;    // 256K floats = 1MB (fits in 6MB)

  preproc_wconv<<<8192, 256, 0, stream>>>(in_feats, mul_encs, add_encs, ln_w, ln_b,
                                          values, qkin, in_proj_w, out_proj_w, wqkv, wout);
  gemm_qkv<<<1536, 512, 0, stream>>>(qkin, values, wqkv, in_proj_b, qws, kws, vtws);
  attn_kernel<<<1024, 256, 0, stream>>>(qws, kws, vtws, po0, po1, stats);
  attn_merge<<<4096, 256, 0, stream>>>(po0, po1, stats, attnb);
  gemm_out<<<1024, 256, 0, stream>>>(attnb, wout, out_proj_b, in_feats, out);
}